// Round 7
// baseline (626.025 us; speedup 1.0000x reference)
//
#include <hip/hip_runtime.h>
#include <hip/hip_bf16.h>

// Round 20: gemm_conv v3 — quad-major conflict-free LDS layout (per-lane
// pre-permuted global source + linear gload_lds dest + matching read), and
// conv2 widened to 64Mx256N (4 waves x 64x64 acc, FLOP/LDS-byte 10.7->16).
// conv1 stays 64Mx128N. Template<C,NT>. Round-19 structure otherwise.
// ws layout (floats), total 34,911,808 f = 139.6 MB:
//   yb[0,7077888) t2b[..,28311552) attnb[..,28459008)
//   sc0@28459008 sh0@28459200 sc1@28459392 sh1@28459968 zp@28460544
//   A0 ush @f 28460608 | A1 ush @f 28515904
//   xT ush @f 29013568 | tbT ush @f 30193216
//   pk [33732160, 34911808)

typedef __hip_bfloat16 bf16;
typedef short bf16x8 __attribute__((ext_vector_type(8)));
typedef float f32x4 __attribute__((ext_vector_type(4)));

typedef const __attribute__((address_space(1))) unsigned short* gas_ptr;
typedef __attribute__((address_space(3))) unsigned short* las_ptr;

__device__ __forceinline__ void gload16(const unsigned short* g, unsigned short* l)
{
    __builtin_amdgcn_global_load_lds((gas_ptr)g, (las_ptr)l, 16, 0, 0);
}

__global__ void beacon_kernel(float* out, float val)
{
    out[threadIdx.x] = val;
}

// ------- weight reorder: src f32 [O][C][9] -> dst bf16 [O][tap*C+ci] -------
__global__ __launch_bounds__(256)
void wreorder_kernel(const float* __restrict__ src, unsigned short* __restrict__ dst,
                     int C, int n)
{
    int i = blockIdx.x * 256 + threadIdx.x;
    if (i >= n) return;
    int K = C * 9;
    int o = i / K, r = i % K;
    int tap = r / C, ci = r % C;
    float v = src[(size_t)o * K + ci * 9 + tap];
    bf16 h = __float2bfloat16(v);
    dst[i] = *reinterpret_cast<unsigned short*>(&h);
}

// ---------------- BN scale/shift precompute + zero page --------------------
__global__ __launch_bounds__(256)
void bnfold_kernel(const float* g0, const float* b0, const float* be0,
                   const float* m0, const float* v0,
                   const float* g1, const float* b1, const float* be1,
                   const float* m1, const float* v1,
                   float* sc0, float* sh0, float* sc1, float* sh1, float* zpf)
{
    int i = blockIdx.x * 256 + threadIdx.x;
    if (i < 192) {
        float s = g0[i] * rsqrtf(v0[i] + 1e-5f);
        sc0[i] = s;
        sh0[i] = (b0[i] - m0[i]) * s + be0[i];
    } else if (i < 768) {
        int c = i - 192;
        float s = g1[c] * rsqrtf(v1[c] + 1e-5f);
        sc1[c] = s;
        sh1[c] = (b1[c] - m1[c]) * s + be1[c];
    } else if (i < 832) {
        zpf[i - 768] = 0.f;
    }
}

// ------- transpose: x f32 [B][64][9216] -> xT bf16 [B][9216][64] -----------
__global__ __launch_bounds__(256)
void txpose_kernel(const float* __restrict__ src, unsigned short* __restrict__ dst,
                   int C)
{
    __shared__ float tile[64][65];
    const int p0 = blockIdx.x * 64, c0 = blockIdx.y * 64;
    src += (size_t)blockIdx.z * C * 9216;
    dst += (size_t)blockIdx.z * 9216 * C;
    for (int i = threadIdx.x; i < 4096; i += 256) {
        int r = i >> 6, c = i & 63;
        tile[c][r] = src[(size_t)(c0 + r) * 9216 + p0 + c];
    }
    __syncthreads();
    for (int i = threadIdx.x; i < 2048; i += 256) {
        int p = i >> 5, cp = (i & 31) * 2;
        bf16 h0 = __float2bfloat16(tile[p][cp]);
        bf16 h1 = __float2bfloat16(tile[p][cp + 1]);
        unsigned int u = (unsigned int)(*reinterpret_cast<unsigned short*>(&h0))
                       | ((unsigned int)(*reinterpret_cast<unsigned short*>(&h1)) << 16);
        *reinterpret_cast<unsigned int*>(dst + (size_t)(p0 + p) * C + c0 + cp) = u;
    }
}

// ------- fused build_t + transpose -> tbT bf16 [B][9216][192]; grid (144,3,B)
__global__ __launch_bounds__(256)
void build_tT(const float* __restrict__ y, unsigned short* __restrict__ tbT)
{
    __shared__ float tile[64][65];
    const int p0 = blockIdx.x * 64, c0 = blockIdx.y * 64;
    y += (size_t)blockIdx.z * 192 * 9216;
    tbT += (size_t)blockIdx.z * 9216 * 192;
    for (int i = threadIdx.x; i < 4096; i += 256) {
        int r = i >> 6, pcol = i & 63;
        const int c = c0 + r;
        const int pix = p0 + pcol;
        const float* yp = y + (size_t)c * 9216;
        float val;
        if (c0 == 64) {
            val = yp[pix];
        } else {
            const int oh = pix / 96, ow = pix % 96;
            float fh = fminf(fmaxf(oh * 0.5f - 0.25f, 0.f), 47.f);
            float fw = fminf(fmaxf(ow * 0.5f - 0.25f, 0.f), 47.f);
            int hlo = (int)floorf(fh);
            int wlo = (int)floorf(fw);
            int hhi = (hlo < 47) ? hlo + 1 : 47;
            int whi = (wlo < 47) ? wlo + 1 : 47;
            float ff = fh - (float)hlo;
            float fg = fw - (float)wlo;
            int hs[2] = {hlo, hhi}, wss[2] = {wlo, whi};
            float p[2][2];
            for (int a = 0; a < 2; ++a)
                for (int e = 0; e < 2; ++e) {
                    const float* q = yp + (hs[a] * 2) * 96 + wss[e] * 2;
                    float v00 = q[0], v01 = q[1], v10 = q[96], v11 = q[97];
                    p[a][e] = (c0 == 0)
                        ? fmaxf(fmaxf(v00, v01), fmaxf(v10, v11))
                        : 0.25f * (v00 + v01 + v10 + v11);
                }
            val = (p[0][0] * (1.f - ff) + p[1][0] * ff) * (1.f - fg)
                + (p[0][1] * (1.f - ff) + p[1][1] * ff) * fg;
        }
        tile[pcol][r] = val;
    }
    __syncthreads();
    for (int i = threadIdx.x; i < 2048; i += 256) {
        int p = i >> 5, cp = (i & 31) * 2;
        bf16 h0 = __float2bfloat16(tile[p][cp]);
        bf16 h1 = __float2bfloat16(tile[p][cp + 1]);
        unsigned int u = (unsigned int)(*reinterpret_cast<unsigned short*>(&h0))
                       | ((unsigned int)(*reinterpret_cast<unsigned short*>(&h1)) << 16);
        *reinterpret_cast<unsigned int*>(tbT + (size_t)(p0 + p) * 192 + c0 + cp) = u;
    }
}

// ------- implicit-im2col GEMM v3 -------------------------------------------
// out[B][M][9216] = A[M][9C] conv BT[B][9216][C], +BN+ReLU.
// Tile 64M x NT(N), BK=32, dbuf, 1 barrier/step. 4 waves x (64 x NT/4) acc.
// Quad-major LDS: As_t[quad][64][16B], Bs_t[quad][NT][16B] — staged with
// per-lane permuted global source into linear lane*16 dests; fragment reads
// are 16-lane-contiguous 256B (2 lanes/bank = conflict-free).
// gridDim = (9216/NT, M/64, B). C % 32 == 0, NT in {128, 256}.
template<int C, int NT>
__global__ __launch_bounds__(256)
void gemm_conv(const unsigned short* __restrict__ A,
               const unsigned short* __restrict__ BT,
               const unsigned short* __restrict__ zp,
               const float* __restrict__ sc, const float* __restrict__ sh,
               float* __restrict__ out, int M)
{
    constexpr int K = 9 * C;
    constexpr int kc = C / 32;         // K-steps per tap
    constexpr int nsteps = 9 * kc;
    constexpr int CPQ = NT / 64;       // 1KB chunks per quad section of Bs
    constexpr int NG  = NT / 64;       // B gloads per thread
    constexpr int NREP = NT / 64;      // B frags (n-rep) per wave

    __shared__ __align__(16) unsigned short As[2][64 * 32];   // 2 x 4 KB
    __shared__ __align__(16) unsigned short Bs[2][NT * 32];   // 2 x NT/16 KB

    const int tid  = threadIdx.x;
    const int w    = tid >> 6;
    const int lane = tid & 63;
    const int l15  = lane & 15, quad = lane >> 4;

    BT  += (size_t)blockIdx.z * 9216 * C;
    out += (size_t)blockIdx.z * (size_t)M * 9216;

    const int row0 = blockIdx.y * 64;
    const int p0   = blockIdx.x * NT;

    f32x4 acc[4][NREP];
#pragma unroll
    for (int m = 0; m < 4; ++m)
#pragma unroll
        for (int n = 0; n < NREP; ++n) acc[m][n] = {0.f, 0.f, 0.f, 0.f};

    // A: thread stages row (row0+lane), ushort cols [w*8, w*8+8) of each K-tile
    const unsigned short* gA = A + (size_t)(row0 + lane) * K + w * 8;
    // B: thread owns ONE pixel row; NG gloads cover NG quad-col slots
    const int pixB = p0 + (w & (CPQ - 1)) * 64 + lane;
    const int hB = pixB / 96, wB = pixB % 96;
    const unsigned short* gB = BT + (size_t)pixB * C;

    unsigned short* lA[2] = { &As[0][w * 512], &As[1][w * 512] };

    auto STAGE = [&](int pb, int tap, int kk) {
        const int dh = tap / 3 - 1, dw = tap % 3 - 1;
        const int off = dh * 96 + dw;
        gload16(gA + tap * C + kk, lA[pb]);
        const bool v = ((unsigned)(hB + dh) < 96u) && ((unsigned)(wB + dw) < 96u);
        const unsigned short* sb = gB + (ptrdiff_t)off * C + kk;
#pragma unroll
        for (int g = 0; g < NG; ++g) {
            const int q = (g * 4 + w) / CPQ;   // quad-col slot this gload fills
            gload16(v ? (sb + q * 8) : zp, &Bs[pb][(g * 4 + w) * 512]);
        }
    };

    STAGE(0, 0, 0);
    __syncthreads();

    int tap_s = 0, kk_s = 32;
    if (kk_s == C) { kk_s = 0; tap_s = 1; }
    int pb = 0;

    for (int s = 0; s < nsteps; ++s) {
        if (s + 1 < nsteps) {
            STAGE(pb ^ 1, tap_s, kk_s);
            kk_s += 32;
            if (kk_s == C) { kk_s = 0; ++tap_s; }
        }

        bf16x8 a[4], b[NREP];
#pragma unroll
        for (int m = 0; m < 4; ++m)
            a[m] = *reinterpret_cast<const bf16x8*>(
                &As[pb][quad * 512 + (m * 16 + l15) * 8]);
#pragma unroll
        for (int n = 0; n < NREP; ++n)
            b[n] = *reinterpret_cast<const bf16x8*>(
                &Bs[pb][quad * (NT * 8) + (w * (NT / 4) + n * 16 + l15) * 8]);

#pragma unroll
        for (int m = 0; m < 4; ++m)
#pragma unroll
            for (int n = 0; n < NREP; ++n)
                acc[m][n] = __builtin_amdgcn_mfma_f32_16x16x32_bf16(
                    a[m], b[n], acc[m][n], 0, 0, 0);

        __syncthreads();
        pb ^= 1;
    }

#pragma unroll
    for (int m = 0; m < 4; ++m) {
        const int co = row0 + m * 16 + quad * 4;
#pragma unroll
        for (int n = 0; n < NREP; ++n) {
            const int pix = p0 + w * (NT / 4) + n * 16 + l15;
#pragma unroll
            for (int r = 0; r < 4; ++r) {
                const int c = co + r;
                float v = acc[m][n][r] * sc[c] + sh[c];
                out[(size_t)c * 9216 + pix] = fmaxf(v, 0.f);
            }
        }
    }
}

// ------------- l2norm rows (block per row, shuffle reduce); grid (384,B) ---
__global__ __launch_bounds__(256)
void l2norm_rows(float* __restrict__ t2)
{
    const int c = blockIdx.x;
    float* p = t2 + (size_t)blockIdx.y * 5308416 + (size_t)c * 9216;
    float s = 0.f;
    for (int i = threadIdx.x; i < 9216; i += 256) { float v = p[i]; s += v * v; }
    for (int off = 32; off; off >>= 1) s += __shfl_xor(s, off, 64);
    __shared__ float red[4];
    if ((threadIdx.x & 63) == 0) red[threadIdx.x >> 6] = s;
    __syncthreads();
    float tot = red[0] + red[1] + red[2] + red[3];
    float inv = 1.f / fmaxf(sqrtf(tot), 1e-12f);
    for (int i = threadIdx.x; i < 9216; i += 256) p[i] *= inv;
}

// -------- qk split-K partial: pk[b][z][c][d], 64x64 tile, 4x4/thread -------
__global__ __launch_bounds__(256)
void qk_partial(const float* __restrict__ t2, float* __restrict__ pk)
{
    __shared__ __align__(16) float qs[32][68];
    __shared__ __align__(16) float ks[32][68];
    const int c0 = blockIdx.y * 64, d0 = blockIdx.x * 64;
    const int bz = blockIdx.z, bb = bz >> 3, chunk = bz & 7;
    const int kbase = chunk * 1152;
    const int tid = threadIdx.x, tx = tid & 15, ty = tid >> 4;
    const float* qb = t2 + (size_t)bb * 5308416;
    const float* kb = qb + (size_t)192 * 9216;

    float acc[4][4];
#pragma unroll
    for (int i = 0; i < 4; ++i)
#pragma unroll
        for (int j = 0; j < 4; ++j) acc[i][j] = 0.f;

    for (int n0 = 0; n0 < 1152; n0 += 32) {
        for (int i = tid; i < 512; i += 256) {
            int row = i >> 3, col = (i & 7) * 4;
            f32x4 v = *reinterpret_cast<const f32x4*>(
                qb + (size_t)(c0 + row) * 9216 + kbase + n0 + col);
            qs[col + 0][row] = v[0];
            qs[col + 1][row] = v[1];
            qs[col + 2][row] = v[2];
            qs[col + 3][row] = v[3];
            f32x4 w = *reinterpret_cast<const f32x4*>(
                kb + (size_t)(d0 + row) * 9216 + kbase + n0 + col);
            ks[col + 0][row] = w[0];
            ks[col + 1][row] = w[1];
            ks[col + 2][row] = w[2];
            ks[col + 3][row] = w[3];
        }
        __syncthreads();
#pragma unroll
        for (int kk = 0; kk < 32; ++kk) {
            f32x4 q4 = *reinterpret_cast<const f32x4*>(&qs[kk][ty * 4]);
            f32x4 k4 = *reinterpret_cast<const f32x4*>(&ks[kk][tx * 4]);
#pragma unroll
            for (int i = 0; i < 4; ++i)
#pragma unroll
                for (int j = 0; j < 4; ++j)
                    acc[i][j] += q4[i] * k4[j];
        }
        __syncthreads();
    }

    float* dst = pk + (size_t)bz * 36864;
#pragma unroll
    for (int i = 0; i < 4; ++i)
#pragma unroll
        for (int j = 0; j < 4; ++j)
            dst[(size_t)(c0 + ty * 4 + i) * 192 + d0 + tx * 4 + j] = acc[i][j];
}

// -------- qk reduce: attn[b][i] = temp * sum_z pk[b][z][i]; grid (144,B) ---
__global__ __launch_bounds__(256)
void qk_reduce(const float* __restrict__ pk, const float* __restrict__ temp,
               float* __restrict__ attn)
{
    const int i = blockIdx.x * 256 + threadIdx.x;
    if (i >= 36864) return;
    const int bb = blockIdx.y;
    const float* src = pk + (size_t)bb * 8 * 36864;
    float s = 0.f;
#pragma unroll
    for (int k = 0; k < 8; ++k)
        s += src[(size_t)k * 36864 + i];
    attn[(size_t)bb * 36864 + i] = s * temp[0];
}

// ---------------- softmax over last dim (192); grid (192*B) ----------------
__global__ __launch_bounds__(64)
void softmax192(float* __restrict__ attn)
{
    float* p = attn + (size_t)blockIdx.x * 192;
    const int t = threadIdx.x;
    float e0 = p[t], e1 = p[t + 64], e2 = p[t + 128];
    float m = fmaxf(e0, fmaxf(e1, e2));
    for (int off = 32; off; off >>= 1) m = fmaxf(m, __shfl_xor(m, off, 64));
    e0 = __expf(e0 - m); e1 = __expf(e1 - m); e2 = __expf(e2 - m);
    float s = e0 + e1 + e2;
    for (int off = 32; off; off >>= 1) s += __shfl_xor(s, off, 64);
    float inv = 1.f / s;
    p[t] = e0 * inv; p[t + 64] = e1 * inv; p[t + 128] = e2 * inv;
}

// ------- ao = attn @ v; grid (36, 12, B) -----------------------------------
__global__ __launch_bounds__(256)
void attn_v(const float* __restrict__ attn, const float* __restrict__ t2,
            float* __restrict__ ao)
{
    __shared__ float aL[192 * 16];
    const int c0 = blockIdx.y * 16;
    const int n = blockIdx.x * 256 + threadIdx.x;
    attn += (size_t)blockIdx.z * 36864;
    t2   += (size_t)blockIdx.z * 5308416;
    ao   += (size_t)blockIdx.z * 1769472;
    for (int i = threadIdx.x; i < 3072; i += 256) {
        int d = i >> 4, cc = i & 15;
        aL[d * 16 + cc] = attn[(size_t)(c0 + cc) * 192 + d];
    }
    __syncthreads();
    const float* vb = t2 + (size_t)384 * 9216;
    f32x4 acc[4];
#pragma unroll
    for (int j = 0; j < 4; ++j) acc[j] = {0.f, 0.f, 0.f, 0.f};
    for (int d = 0; d < 192; ++d) {
        float vv = vb[(size_t)d * 9216 + n];
        const f32x4* ap = reinterpret_cast<const f32x4*>(&aL[d * 16]);
#pragma unroll
        for (int j = 0; j < 4; ++j) {
            f32x4 a = ap[j];
            acc[j][0] += a[0] * vv;
            acc[j][1] += a[1] * vv;
            acc[j][2] += a[2] * vv;
            acc[j][3] += a[3] * vv;
        }
    }
#pragma unroll
    for (int j = 0; j < 4; ++j)
#pragma unroll
        for (int r = 0; r < 4; ++r)
            ao[(size_t)(c0 + j * 4 + r) * 9216 + n] = acc[j][r];
}

// ---------------- depthwise 3x3 + bias -> fp32 out; grid (36,192,B) --------
__global__ __launch_bounds__(256)
void dwconv(const float* __restrict__ ao, const float* __restrict__ w2,
            const float* __restrict__ bias2, float* __restrict__ out)
{
    const int c = blockIdx.y;
    const int pix = blockIdx.x * 256 + threadIdx.x;
    const int h = pix / 96, w = pix % 96;
    const float* sp = ao + (size_t)blockIdx.z * 1769472 + (size_t)c * 9216;
    float acc = bias2[c];
#pragma unroll
    for (int kh = 0; kh < 3; ++kh) {
        int hh = h + kh - 1;
        if (hh < 0 || hh >= 96) continue;
#pragma unroll
        for (int kw = 0; kw < 3; ++kw) {
            int ww = w + kw - 1;
            if (ww < 0 || ww >= 96) continue;
            acc += w2[c * 9 + kh * 3 + kw] * sp[hh * 96 + ww];
        }
    }
    out[(size_t)blockIdx.z * 1769472 + (size_t)c * 9216 + pix] = acc;
}

extern "C" void kernel_launch(void* const* d_in, const int* in_sizes, int n_in,
                              void* d_out, int out_size, void* d_ws, size_t ws_size,
                              hipStream_t stream)
{
    float* out = (float*)d_out;

    static const int expected_sizes[16] = {
        2359296, 110592, 192, 192, 192, 192, 192,
        995328, 576, 576, 576, 576, 576, 1, 1728, 192
    };
    if (n_in != 16) {
        beacon_kernel<<<1, 256, 0, stream>>>(out, 100000.f + (float)n_in);
        return;
    }
    for (int i = 0; i < 16; ++i) {
        if (in_sizes[i] != expected_sizes[i]) {
            beacon_kernel<<<1, 256, 0, stream>>>(out, 1000.f * (float)(i + 1));
            return;
        }
    }
    if (out_size != 7077888) {
        beacon_kernel<<<1, 256, 0, stream>>>(out, 50000.f);
        return;
    }
    const size_t needed = (size_t)34911808 * 4;  // 139.6 MB
    if (ws_size < needed) {
        beacon_kernel<<<1, 256, 0, stream>>>(out, 200.f + (float)(ws_size >> 20));
        return;
    }

    const float* x    = (const float*)d_in[0];
    const float* w0   = (const float*)d_in[1];
    const float* b0   = (const float*)d_in[2];
    const float* g0   = (const float*)d_in[3];
    const float* be0  = (const float*)d_in[4];
    const float* m0   = (const float*)d_in[5];
    const float* v0   = (const float*)d_in[6];
    const float* w1   = (const float*)d_in[7];
    const float* b1   = (const float*)d_in[8];
    const float* g1   = (const float*)d_in[9];
    const float* be1  = (const float*)d_in[10];
    const float* m1   = (const float*)d_in[11];
    const float* v1   = (const float*)d_in[12];
    const float* temp = (const float*)d_in[13];
    const float* w2   = (const float*)d_in[14];
    const float* bi2  = (const float*)d_in[15];

    float* ws    = (float*)d_ws;
    float* yb    = ws;                        // 4 x 1,769,472 f
    float* t2b   = ws + 7077888;              // 4 x 5,308,416 f
    float* attnb = ws + 28311552;             // 4 x 36,864 f
    float* sc0   = ws + 28459008;
    float* sh0   = ws + 28459200;
    float* sc1   = ws + 28459392;
    float* sh1   = ws + 28459968;
    float* zpf   = ws + 28460544;             // 64 f zero page
    unsigned short* zp  = (unsigned short*)zpf;
    unsigned short* A0  = (unsigned short*)(ws + 28460608);  // 110,592 bf16
    unsigned short* A1  = (unsigned short*)(ws + 28515904);  // 995,328 bf16
    unsigned short* xT  = (unsigned short*)(ws + 29013568);  // 4 x 9216x64 bf16
    unsigned short* tbT = (unsigned short*)(ws + 30193216);  // 4 x 9216x192 bf16
    float* pk  = ws + 33732160;               // 4 x 8 x 36864 f
    float* aob = yb;  // alias: yb dead after build_tT

    wreorder_kernel<<<dim3(432), dim3(256), 0, stream>>>(w0, A0, 64, 110592);
    wreorder_kernel<<<dim3(3888), dim3(256), 0, stream>>>(w1, A1, 192, 995328);
    bnfold_kernel<<<dim3(4), dim3(256), 0, stream>>>(g0, b0, be0, m0, v0,
                                                     g1, b1, be1, m1, v1,
                                                     sc0, sh0, sc1, sh1, zpf);

    txpose_kernel<<<dim3(144, 1, 4), dim3(256), 0, stream>>>(x, xT, 64);
    gemm_conv<64, 128><<<dim3(72, 3, 4), dim3(256), 0, stream>>>(A0, xT, zp, sc0, sh0, yb, 192);
    build_tT<<<dim3(144, 3, 4), dim3(256), 0, stream>>>(yb, tbT);
    gemm_conv<192, 256><<<dim3(36, 9, 4), dim3(256), 0, stream>>>(A1, tbT, zp, sc1, sh1, t2b, 576);
    l2norm_rows<<<dim3(384, 4), dim3(256), 0, stream>>>(t2b);
    qk_partial<<<dim3(3, 3, 32), dim3(256), 0, stream>>>(t2b, pk);
    qk_reduce<<<dim3(144, 4), dim3(256), 0, stream>>>(pk, temp, attnb);
    softmax192<<<dim3(768), dim3(64), 0, stream>>>(attnb);
    attn_v<<<dim3(36, 12, 4), dim3(256), 0, stream>>>(attnb, t2b, aob);
    dwconv<<<dim3(36, 192, 4), dim3(256), 0, stream>>>(aob, w2, bi2, out);
}

// Round 9
// 494.378 us; speedup vs baseline: 1.2663x; 1.2663x over previous
//
#include <hip/hip_runtime.h>
#include <hip/hip_bf16.h>

// Round 22 (= round 21 resubmit; prior bench was a container infra failure).
// gemm_conv v4 — coalesced staging (round-19 geometry: 4 lanes per 64B
// row-slice) + granule XOR swizzle for conflict-free reads.
// Slot gs = g ^ ((R>>1)&3): write permutes the per-lane GLOBAL source granule
// (same 64B line, coalescing intact, LDS dest linear); read uses
// col = (quad ^ ((l15>>1)&3))*16B -> 2 lanes/bank (free). conv2 NT=256.
// Stage-major batching, 13 launches.
// ws layout (floats), total 34,911,808 f = 139.6 MB:
//   yb[0,7077888) t2b[..,28311552) attnb[..,28459008)
//   sc0@28459008 sh0@28459200 sc1@28459392 sh1@28459968 zp@28460544
//   A0 ush @f 28460608 | A1 ush @f 28515904
//   xT ush @f 29013568 | tbT ush @f 30193216
//   pk [33732160, 34911808)

typedef __hip_bfloat16 bf16;
typedef short bf16x8 __attribute__((ext_vector_type(8)));
typedef float f32x4 __attribute__((ext_vector_type(4)));

typedef const __attribute__((address_space(1))) unsigned short* gas_ptr;
typedef __attribute__((address_space(3))) unsigned short* las_ptr;

__device__ __forceinline__ void gload16(const unsigned short* g, unsigned short* l)
{
    __builtin_amdgcn_global_load_lds((gas_ptr)g, (las_ptr)l, 16, 0, 0);
}

__global__ void beacon_kernel(float* out, float val)
{
    out[threadIdx.x] = val;
}

// ------- weight reorder: src f32 [O][C][9] -> dst bf16 [O][tap*C+ci] -------
__global__ __launch_bounds__(256)
void wreorder_kernel(const float* __restrict__ src, unsigned short* __restrict__ dst,
                     int C, int n)
{
    int i = blockIdx.x * 256 + threadIdx.x;
    if (i >= n) return;
    int K = C * 9;
    int o = i / K, r = i % K;
    int tap = r / C, ci = r % C;
    float v = src[(size_t)o * K + ci * 9 + tap];
    bf16 h = __float2bfloat16(v);
    dst[i] = *reinterpret_cast<unsigned short*>(&h);
}

// ---------------- BN scale/shift precompute + zero page --------------------
__global__ __launch_bounds__(256)
void bnfold_kernel(const float* g0, const float* b0, const float* be0,
                   const float* m0, const float* v0,
                   const float* g1, const float* b1, const float* be1,
                   const float* m1, const float* v1,
                   float* sc0, float* sh0, float* sc1, float* sh1, float* zpf)
{
    int i = blockIdx.x * 256 + threadIdx.x;
    if (i < 192) {
        float s = g0[i] * rsqrtf(v0[i] + 1e-5f);
        sc0[i] = s;
        sh0[i] = (b0[i] - m0[i]) * s + be0[i];
    } else if (i < 768) {
        int c = i - 192;
        float s = g1[c] * rsqrtf(v1[c] + 1e-5f);
        sc1[c] = s;
        sh1[c] = (b1[c] - m1[c]) * s + be1[c];
    } else if (i < 832) {
        zpf[i - 768] = 0.f;
    }
}

// ------- transpose: x f32 [B][64][9216] -> xT bf16 [B][9216][64] -----------
__global__ __launch_bounds__(256)
void txpose_kernel(const float* __restrict__ src, unsigned short* __restrict__ dst,
                   int C)
{
    __shared__ float tile[64][65];
    const int p0 = blockIdx.x * 64, c0 = blockIdx.y * 64;
    src += (size_t)blockIdx.z * C * 9216;
    dst += (size_t)blockIdx.z * 9216 * C;
    for (int i = threadIdx.x; i < 4096; i += 256) {
        int r = i >> 6, c = i & 63;
        tile[c][r] = src[(size_t)(c0 + r) * 9216 + p0 + c];
    }
    __syncthreads();
    for (int i = threadIdx.x; i < 2048; i += 256) {
        int p = i >> 5, cp = (i & 31) * 2;
        bf16 h0 = __float2bfloat16(tile[p][cp]);
        bf16 h1 = __float2bfloat16(tile[p][cp + 1]);
        unsigned int u = (unsigned int)(*reinterpret_cast<unsigned short*>(&h0))
                       | ((unsigned int)(*reinterpret_cast<unsigned short*>(&h1)) << 16);
        *reinterpret_cast<unsigned int*>(dst + (size_t)(p0 + p) * C + c0 + cp) = u;
    }
}

// ------- fused build_t + transpose -> tbT bf16 [B][9216][192]; grid (144,3,B)
__global__ __launch_bounds__(256)
void build_tT(const float* __restrict__ y, unsigned short* __restrict__ tbT)
{
    __shared__ float tile[64][65];
    const int p0 = blockIdx.x * 64, c0 = blockIdx.y * 64;
    y += (size_t)blockIdx.z * 192 * 9216;
    tbT += (size_t)blockIdx.z * 9216 * 192;
    for (int i = threadIdx.x; i < 4096; i += 256) {
        int r = i >> 6, pcol = i & 63;
        const int c = c0 + r;
        const int pix = p0 + pcol;
        const float* yp = y + (size_t)c * 9216;
        float val;
        if (c0 == 64) {
            val = yp[pix];
        } else {
            const int oh = pix / 96, ow = pix % 96;
            float fh = fminf(fmaxf(oh * 0.5f - 0.25f, 0.f), 47.f);
            float fw = fminf(fmaxf(ow * 0.5f - 0.25f, 0.f), 47.f);
            int hlo = (int)floorf(fh);
            int wlo = (int)floorf(fw);
            int hhi = (hlo < 47) ? hlo + 1 : 47;
            int whi = (wlo < 47) ? wlo + 1 : 47;
            float ff = fh - (float)hlo;
            float fg = fw - (float)wlo;
            int hs[2] = {hlo, hhi}, wss[2] = {wlo, whi};
            float p[2][2];
            for (int a = 0; a < 2; ++a)
                for (int e = 0; e < 2; ++e) {
                    const float* q = yp + (hs[a] * 2) * 96 + wss[e] * 2;
                    float v00 = q[0], v01 = q[1], v10 = q[96], v11 = q[97];
                    p[a][e] = (c0 == 0)
                        ? fmaxf(fmaxf(v00, v01), fmaxf(v10, v11))
                        : 0.25f * (v00 + v01 + v10 + v11);
                }
            val = (p[0][0] * (1.f - ff) + p[1][0] * ff) * (1.f - fg)
                + (p[0][1] * (1.f - ff) + p[1][1] * ff) * fg;
        }
        tile[pcol][r] = val;
    }
    __syncthreads();
    for (int i = threadIdx.x; i < 2048; i += 256) {
        int p = i >> 5, cp = (i & 31) * 2;
        bf16 h0 = __float2bfloat16(tile[p][cp]);
        bf16 h1 = __float2bfloat16(tile[p][cp + 1]);
        unsigned int u = (unsigned int)(*reinterpret_cast<unsigned short*>(&h0))
                       | ((unsigned int)(*reinterpret_cast<unsigned short*>(&h1)) << 16);
        *reinterpret_cast<unsigned int*>(tbT + (size_t)(p0 + p) * 192 + c0 + cp) = u;
    }
}

// ------- implicit-im2col GEMM v4 -------------------------------------------
// out[B][M][9216] = A[M][9C] conv BT[B][9216][C], +BN+ReLU.
// Tile 64M x NT, BK=32, dbuf, 1 barrier/step. LDS rows = 64B (32 ush);
// granule-swizzled: slot gs holds natural granule gs ^ ((R>>1)&3).
// Staging: thread srow=tid>>2 loads granule (tid&3)^((srow>>1)&3) of its
// 64B row-slice (coalesced); read col = (quad^((l15>>1)&3))*8 ush.
// gridDim = (9216/NT, M/64, B). C % 32 == 0, NT in {128, 256}.
template<int C, int NT>
__global__ __launch_bounds__(256)
void gemm_conv(const unsigned short* __restrict__ A,
               const unsigned short* __restrict__ BT,
               const unsigned short* __restrict__ zp,
               const float* __restrict__ sc, const float* __restrict__ sh,
               float* __restrict__ out, int M)
{
    constexpr int K = 9 * C;
    constexpr int kc = C / 32;
    constexpr int nsteps = 9 * kc;
    constexpr int NSEC = NT / 64;      // 64-row B sections (= gloads/thread)
    constexpr int NREP = NT / 64;      // B frags per wave (wave owns NT/4 rows)

    __shared__ __align__(16) unsigned short As[2][64 * 32];   // 2 x 4 KB
    __shared__ __align__(16) unsigned short Bs[2][NT * 32];   // 2 x NT/16 KB

    const int tid  = threadIdx.x;
    const int w    = tid >> 6;
    const int lane = tid & 63;
    const int l15  = lane & 15, quad = lane >> 4;

    BT  += (size_t)blockIdx.z * 9216 * C;
    out += (size_t)blockIdx.z * (size_t)M * 9216;

    const int row0 = blockIdx.y * 64;
    const int p0   = blockIdx.x * NT;

    f32x4 acc[4][NREP];
#pragma unroll
    for (int m = 0; m < 4; ++m)
#pragma unroll
        for (int n = 0; n < NREP; ++n) acc[m][n] = {0.f, 0.f, 0.f, 0.f};

    // staging geometry: row srow, permuted granule within the 64B slice
    const int srow = tid >> 2;
    const int scol = (((tid & 3) ^ ((srow >> 1) & 3)) << 3);   // ushort col
    const unsigned short* gA = A + (size_t)(row0 + srow) * K + scol;
    int hB[NSEC], wB[NSEC];
    const unsigned short* gB[NSEC];
#pragma unroll
    for (int r = 0; r < NSEC; ++r) {
        int pB = p0 + 64 * r + srow;
        hB[r] = pB / 96;
        wB[r] = pB % 96;
        gB[r] = BT + (size_t)pB * C + scol;
    }

    unsigned short* As0 = &As[0][0];
    unsigned short* Bs0 = &Bs[0][0];

    auto STAGE = [&](int pb, int tap, int kk) {
        const int dh = tap / 3 - 1, dw = tap % 3 - 1;
        const int off = dh * 96 + dw;
        unsigned short* la = As0 + pb * 2048 + w * 512;
        unsigned short* lb = Bs0 + pb * (NT * 32) + w * 512;
        gload16(gA + tap * C + kk, la);
#pragma unroll
        for (int r = 0; r < NSEC; ++r) {
            bool v = ((unsigned)(hB[r] + dh) < 96u) && ((unsigned)(wB[r] + dw) < 96u);
            const unsigned short* s = gB[r] + (ptrdiff_t)off * C + kk;
            gload16(v ? s : zp, lb + r * 2048);
        }
    };

    STAGE(0, 0, 0);
    __syncthreads();

    int tap_s = 0, kk_s = 32;
    if (kk_s == C) { kk_s = 0; tap_s = 1; }
    int pb = 0;

    const int swz8 = (quad ^ ((l15 >> 1) & 3)) * 8;   // read granule (ushorts)

    for (int s = 0; s < nsteps; ++s) {
        if (s + 1 < nsteps) {
            STAGE(pb ^ 1, tap_s, kk_s);
            kk_s += 32;
            if (kk_s == C) { kk_s = 0; ++tap_s; }
        }

        const unsigned short* Ab = As0 + pb * 2048;
        const unsigned short* Bb = Bs0 + pb * (NT * 32);
        bf16x8 a[4], b[NREP];
#pragma unroll
        for (int m = 0; m < 4; ++m)
            a[m] = *reinterpret_cast<const bf16x8*>(Ab + (m * 16 + l15) * 32 + swz8);
#pragma unroll
        for (int n = 0; n < NREP; ++n)
            b[n] = *reinterpret_cast<const bf16x8*>(
                Bb + (w * (NT / 4) + n * 16 + l15) * 32 + swz8);

#pragma unroll
        for (int m = 0; m < 4; ++m)
#pragma unroll
            for (int n = 0; n < NREP; ++n)
                acc[m][n] = __builtin_amdgcn_mfma_f32_16x16x32_bf16(
                    a[m], b[n], acc[m][n], 0, 0, 0);

        __syncthreads();
        pb ^= 1;
    }

#pragma unroll
    for (int m = 0; m < 4; ++m) {
        const int co = row0 + m * 16 + quad * 4;
#pragma unroll
        for (int n = 0; n < NREP; ++n) {
            const int pix = p0 + w * (NT / 4) + n * 16 + l15;
#pragma unroll
            for (int r = 0; r < 4; ++r) {
                const int c = co + r;
                float v = acc[m][n][r] * sc[c] + sh[c];
                out[(size_t)c * 9216 + pix] = fmaxf(v, 0.f);
            }
        }
    }
}

// ------------- l2norm rows (block per row, shuffle reduce); grid (384,B) ---
__global__ __launch_bounds__(256)
void l2norm_rows(float* __restrict__ t2)
{
    const int c = blockIdx.x;
    float* p = t2 + (size_t)blockIdx.y * 5308416 + (size_t)c * 9216;
    float s = 0.f;
    for (int i = threadIdx.x; i < 9216; i += 256) { float v = p[i]; s += v * v; }
    for (int off = 32; off; off >>= 1) s += __shfl_xor(s, off, 64);
    __shared__ float red[4];
    if ((threadIdx.x & 63) == 0) red[threadIdx.x >> 6] = s;
    __syncthreads();
    float tot = red[0] + red[1] + red[2] + red[3];
    float inv = 1.f / fmaxf(sqrtf(tot), 1e-12f);
    for (int i = threadIdx.x; i < 9216; i += 256) p[i] *= inv;
}

// -------- qk split-K partial: pk[b][z][c][d], 64x64 tile, 4x4/thread -------
__global__ __launch_bounds__(256)
void qk_partial(const float* __restrict__ t2, float* __restrict__ pk)
{
    __shared__ __align__(16) float qs[32][68];
    __shared__ __align__(16) float ks[32][68];
    const int c0 = blockIdx.y * 64, d0 = blockIdx.x * 64;
    const int bz = blockIdx.z, bb = bz >> 3, chunk = bz & 7;
    const int kbase = chunk * 1152;
    const int tid = threadIdx.x, tx = tid & 15, ty = tid >> 4;
    const float* qb = t2 + (size_t)bb * 5308416;
    const float* kb = qb + (size_t)192 * 9216;

    float acc[4][4];
#pragma unroll
    for (int i = 0; i < 4; ++i)
#pragma unroll
        for (int j = 0; j < 4; ++j) acc[i][j] = 0.f;

    for (int n0 = 0; n0 < 1152; n0 += 32) {
        for (int i = tid; i < 512; i += 256) {
            int row = i >> 3, col = (i & 7) * 4;
            f32x4 v = *reinterpret_cast<const f32x4*>(
                qb + (size_t)(c0 + row) * 9216 + kbase + n0 + col);
            qs[col + 0][row] = v[0];
            qs[col + 1][row] = v[1];
            qs[col + 2][row] = v[2];
            qs[col + 3][row] = v[3];
            f32x4 w = *reinterpret_cast<const f32x4*>(
                kb + (size_t)(d0 + row) * 9216 + kbase + n0 + col);
            ks[col + 0][row] = w[0];
            ks[col + 1][row] = w[1];
            ks[col + 2][row] = w[2];
            ks[col + 3][row] = w[3];
        }
        __syncthreads();
#pragma unroll
        for (int kk = 0; kk < 32; ++kk) {
            f32x4 q4 = *reinterpret_cast<const f32x4*>(&qs[kk][ty * 4]);
            f32x4 k4 = *reinterpret_cast<const f32x4*>(&ks[kk][tx * 4]);
#pragma unroll
            for (int i = 0; i < 4; ++i)
#pragma unroll
                for (int j = 0; j < 4; ++j)
                    acc[i][j] += q4[i] * k4[j];
        }
        __syncthreads();
    }

    float* dst = pk + (size_t)bz * 36864;
#pragma unroll
    for (int i = 0; i < 4; ++i)
#pragma unroll
        for (int j = 0; j < 4; ++j)
            dst[(size_t)(c0 + ty * 4 + i) * 192 + d0 + tx * 4 + j] = acc[i][j];
}

// -------- qk reduce: attn[b][i] = temp * sum_z pk[b][z][i]; grid (144,B) ---
__global__ __launch_bounds__(256)
void qk_reduce(const float* __restrict__ pk, const float* __restrict__ temp,
               float* __restrict__ attn)
{
    const int i = blockIdx.x * 256 + threadIdx.x;
    if (i >= 36864) return;
    const int bb = blockIdx.y;
    const float* src = pk + (size_t)bb * 8 * 36864;
    float s = 0.f;
#pragma unroll
    for (int k = 0; k < 8; ++k)
        s += src[(size_t)k * 36864 + i];
    attn[(size_t)bb * 36864 + i] = s * temp[0];
}

// ---------------- softmax over last dim (192); grid (192*B) ----------------
__global__ __launch_bounds__(64)
void softmax192(float* __restrict__ attn)
{
    float* p = attn + (size_t)blockIdx.x * 192;
    const int t = threadIdx.x;
    float e0 = p[t], e1 = p[t + 64], e2 = p[t + 128];
    float m = fmaxf(e0, fmaxf(e1, e2));
    for (int off = 32; off; off >>= 1) m = fmaxf(m, __shfl_xor(m, off, 64));
    e0 = __expf(e0 - m); e1 = __expf(e1 - m); e2 = __expf(e2 - m);
    float s = e0 + e1 + e2;
    for (int off = 32; off; off >>= 1) s += __shfl_xor(s, off, 64);
    float inv = 1.f / s;
    p[t] = e0 * inv; p[t + 64] = e1 * inv; p[t + 128] = e2 * inv;
}

// ------- ao = attn @ v; grid (36, 12, B) -----------------------------------
__global__ __launch_bounds__(256)
void attn_v(const float* __restrict__ attn, const float* __restrict__ t2,
            float* __restrict__ ao)
{
    __shared__ float aL[192 * 16];
    const int c0 = blockIdx.y * 16;
    const int n = blockIdx.x * 256 + threadIdx.x;
    attn += (size_t)blockIdx.z * 36864;
    t2   += (size_t)blockIdx.z * 5308416;
    ao   += (size_t)blockIdx.z * 1769472;
    for (int i = threadIdx.x; i < 3072; i += 256) {
        int d = i >> 4, cc = i & 15;
        aL[d * 16 + cc] = attn[(size_t)(c0 + cc) * 192 + d];
    }
    __syncthreads();
    const float* vb = t2 + (size_t)384 * 9216;
    f32x4 acc[4];
#pragma unroll
    for (int j = 0; j < 4; ++j) acc[j] = {0.f, 0.f, 0.f, 0.f};
    for (int d = 0; d < 192; ++d) {
        float vv = vb[(size_t)d * 9216 + n];
        const f32x4* ap = reinterpret_cast<const f32x4*>(&aL[d * 16]);
#pragma unroll
        for (int j = 0; j < 4; ++j) {
            f32x4 a = ap[j];
            acc[j][0] += a[0] * vv;
            acc[j][1] += a[1] * vv;
            acc[j][2] += a[2] * vv;
            acc[j][3] += a[3] * vv;
        }
    }
#pragma unroll
    for (int j = 0; j < 4; ++j)
#pragma unroll
        for (int r = 0; r < 4; ++r)
            ao[(size_t)(c0 + j * 4 + r) * 9216 + n] = acc[j][r];
}

// ---------------- depthwise 3x3 + bias -> fp32 out; grid (36,192,B) --------
__global__ __launch_bounds__(256)
void dwconv(const float* __restrict__ ao, const float* __restrict__ w2,
            const float* __restrict__ bias2, float* __restrict__ out)
{
    const int c = blockIdx.y;
    const int pix = blockIdx.x * 256 + threadIdx.x;
    const int h = pix / 96, w = pix % 96;
    const float* sp = ao + (size_t)blockIdx.z * 1769472 + (size_t)c * 9216;
    float acc = bias2[c];
#pragma unroll
    for (int kh = 0; kh < 3; ++kh) {
        int hh = h + kh - 1;
        if (hh < 0 || hh >= 96) continue;
#pragma unroll
        for (int kw = 0; kw < 3; ++kw) {
            int ww = w + kw - 1;
            if (ww < 0 || ww >= 96) continue;
            acc += w2[c * 9 + kh * 3 + kw] * sp[hh * 96 + ww];
        }
    }
    out[(size_t)blockIdx.z * 1769472 + (size_t)c * 9216 + pix] = acc;
}

extern "C" void kernel_launch(void* const* d_in, const int* in_sizes, int n_in,
                              void* d_out, int out_size, void* d_ws, size_t ws_size,
                              hipStream_t stream)
{
    float* out = (float*)d_out;

    static const int expected_sizes[16] = {
        2359296, 110592, 192, 192, 192, 192, 192,
        995328, 576, 576, 576, 576, 576, 1, 1728, 192
    };
    if (n_in != 16) {
        beacon_kernel<<<1, 256, 0, stream>>>(out, 100000.f + (float)n_in);
        return;
    }
    for (int i = 0; i < 16; ++i) {
        if (in_sizes[i] != expected_sizes[i]) {
            beacon_kernel<<<1, 256, 0, stream>>>(out, 1000.f * (float)(i + 1));
            return;
        }
    }
    if (out_size != 7077888) {
        beacon_kernel<<<1, 256, 0, stream>>>(out, 50000.f);
        return;
    }
    const size_t needed = (size_t)34911808 * 4;  // 139.6 MB
    if (ws_size < needed) {
        beacon_kernel<<<1, 256, 0, stream>>>(out, 200.f + (float)(ws_size >> 20));
        return;
    }

    const float* x    = (const float*)d_in[0];
    const float* w0   = (const float*)d_in[1];
    const float* b0   = (const float*)d_in[2];
    const float* g0   = (const float*)d_in[3];
    const float* be0  = (const float*)d_in[4];
    const float* m0   = (const float*)d_in[5];
    const float* v0   = (const float*)d_in[6];
    const float* w1   = (const float*)d_in[7];
    const float* b1   = (const float*)d_in[8];
    const float* g1   = (const float*)d_in[9];
    const float* be1  = (const float*)d_in[10];
    const float* m1   = (const float*)d_in[11];
    const float* v1   = (const float*)d_in[12];
    const float* temp = (const float*)d_in[13];
    const float* w2   = (const float*)d_in[14];
    const float* bi2  = (const float*)d_in[15];

    float* ws    = (float*)d_ws;
    float* yb    = ws;                        // 4 x 1,769,472 f
    float* t2b   = ws + 7077888;              // 4 x 5,308,416 f
    float* attnb = ws + 28311552;             // 4 x 36,864 f
    float* sc0   = ws + 28459008;
    float* sh0   = ws + 28459200;
    float* sc1   = ws + 28459392;
    float* sh1   = ws + 28459968;
    float* zpf   = ws + 28460544;             // 64 f zero page
    unsigned short* zp  = (unsigned short*)zpf;
    unsigned short* A0  = (unsigned short*)(ws + 28460608);  // 110,592 bf16
    unsigned short* A1  = (unsigned short*)(ws + 28515904);  // 995,328 bf16
    unsigned short* xT  = (unsigned short*)(ws + 29013568);  // 4 x 9216x64 bf16
    unsigned short* tbT = (unsigned short*)(ws + 30193216);  // 4 x 9216x192 bf16
    float* pk  = ws + 33732160;               // 4 x 8 x 36864 f
    float* aob = yb;  // alias: yb dead after build_tT

    wreorder_kernel<<<dim3(432), dim3(256), 0, stream>>>(w0, A0, 64, 110592);
    wreorder_kernel<<<dim3(3888), dim3(256), 0, stream>>>(w1, A1, 192, 995328);
    bnfold_kernel<<<dim3(4), dim3(256), 0, stream>>>(g0, b0, be0, m0, v0,
                                                     g1, b1, be1, m1, v1,
                                                     sc0, sh0, sc1, sh1, zpf);

    txpose_kernel<<<dim3(144, 1, 4), dim3(256), 0, stream>>>(x, xT, 64);
    gemm_conv<64, 128><<<dim3(72, 3, 4), dim3(256), 0, stream>>>(A0, xT, zp, sc0, sh0, yb, 192);
    build_tT<<<dim3(144, 3, 4), dim3(256), 0, stream>>>(yb, tbT);
    gemm_conv<192, 256><<<dim3(36, 9, 4), dim3(256), 0, stream>>>(A1, tbT, zp, sc1, sh1, t2b, 576);
    l2norm_rows<<<dim3(384, 4), dim3(256), 0, stream>>>(t2b);
    qk_partial<<<dim3(3, 3, 32), dim3(256), 0, stream>>>(t2b, pk);
    qk_reduce<<<dim3(144, 4), dim3(256), 0, stream>>>(pk, temp, attnb);
    softmax192<<<dim3(768), dim3(64), 0, stream>>>(attnb);
    attn_v<<<dim3(36, 12, 4), dim3(256), 0, stream>>>(attnb, t2b, aob);
    dwconv<<<dim3(36, 192, 4), dim3(256), 0, stream>>>(aob, w2, bi2, out);
}

// Round 10
// 480.305 us; speedup vs baseline: 1.3034x; 1.0293x over previous
//
#include <hip/hip_runtime.h>
#include <hip/hip_bf16.h>

// Round 23: gemm_conv v5 — VALU-diet staging (r9 profile: VALUBusy 54% >
// MfmaUtil 22% -> address machinery bound).
//  * k = tap*C+ci is LINEAR in k: A source ptr += 32/step, no tap math.
//  * per-thread 9-bit tap validity masks computed once.
//  * B source ptrs sel[r] re-selected (real vs zero page) only at tap
//    boundaries; within a tap sel[r] += 32 (zero page 256 f covers drift).
//  * step loop unrolled x2 -> ping-pong index compile-time -> LDS immediates.
// Swizzle/mapping identical to v4 (numerically proven).
// ws layout (floats), total 34,912,000 f = 139.65 MB:
//   yb[0,7077888) t2b[..,28311552) attnb[..,28459008)
//   sc0@28459008 sh0@28459200 sc1@28459392 sh1@28459968 zp@28460544 (256 f)
//   A0 ush @f 28460800 | A1 ush @f 28516096
//   xT ush @f 29013760 | tbT ush @f 30193408
//   pk [33732352, 34912000)

typedef __hip_bfloat16 bf16;
typedef short bf16x8 __attribute__((ext_vector_type(8)));
typedef float f32x4 __attribute__((ext_vector_type(4)));

typedef const __attribute__((address_space(1))) unsigned short* gas_ptr;
typedef __attribute__((address_space(3))) unsigned short* las_ptr;

__device__ __forceinline__ void gload16(const unsigned short* g, unsigned short* l)
{
    __builtin_amdgcn_global_load_lds((gas_ptr)g, (las_ptr)l, 16, 0, 0);
}

__global__ void beacon_kernel(float* out, float val)
{
    out[threadIdx.x] = val;
}

// ------- weight reorder: src f32 [O][C][9] -> dst bf16 [O][tap*C+ci] -------
__global__ __launch_bounds__(256)
void wreorder_kernel(const float* __restrict__ src, unsigned short* __restrict__ dst,
                     int C, int n)
{
    int i = blockIdx.x * 256 + threadIdx.x;
    if (i >= n) return;
    int K = C * 9;
    int o = i / K, r = i % K;
    int tap = r / C, ci = r % C;
    float v = src[(size_t)o * K + ci * 9 + tap];
    bf16 h = __float2bfloat16(v);
    dst[i] = *reinterpret_cast<unsigned short*>(&h);
}

// ---------------- BN scale/shift precompute + zero page (256 f) ------------
__global__ __launch_bounds__(256)
void bnfold_kernel(const float* g0, const float* b0, const float* be0,
                   const float* m0, const float* v0,
                   const float* g1, const float* b1, const float* be1,
                   const float* m1, const float* v1,
                   float* sc0, float* sh0, float* sc1, float* sh1, float* zpf)
{
    int i = blockIdx.x * 256 + threadIdx.x;
    if (i < 192) {
        float s = g0[i] * rsqrtf(v0[i] + 1e-5f);
        sc0[i] = s;
        sh0[i] = (b0[i] - m0[i]) * s + be0[i];
    } else if (i < 768) {
        int c = i - 192;
        float s = g1[c] * rsqrtf(v1[c] + 1e-5f);
        sc1[c] = s;
        sh1[c] = (b1[c] - m1[c]) * s + be1[c];
    } else if (i < 1024) {
        zpf[i - 768] = 0.f;
    }
}

// ------- transpose: x f32 [B][64][9216] -> xT bf16 [B][9216][64] -----------
__global__ __launch_bounds__(256)
void txpose_kernel(const float* __restrict__ src, unsigned short* __restrict__ dst,
                   int C)
{
    __shared__ float tile[64][65];
    const int p0 = blockIdx.x * 64, c0 = blockIdx.y * 64;
    src += (size_t)blockIdx.z * C * 9216;
    dst += (size_t)blockIdx.z * 9216 * C;
    for (int i = threadIdx.x; i < 4096; i += 256) {
        int r = i >> 6, c = i & 63;
        tile[c][r] = src[(size_t)(c0 + r) * 9216 + p0 + c];
    }
    __syncthreads();
    for (int i = threadIdx.x; i < 2048; i += 256) {
        int p = i >> 5, cp = (i & 31) * 2;
        bf16 h0 = __float2bfloat16(tile[p][cp]);
        bf16 h1 = __float2bfloat16(tile[p][cp + 1]);
        unsigned int u = (unsigned int)(*reinterpret_cast<unsigned short*>(&h0))
                       | ((unsigned int)(*reinterpret_cast<unsigned short*>(&h1)) << 16);
        *reinterpret_cast<unsigned int*>(dst + (size_t)(p0 + p) * C + c0 + cp) = u;
    }
}

// ------- fused build_t + transpose -> tbT bf16 [B][9216][192]; grid (144,3,B)
__global__ __launch_bounds__(256)
void build_tT(const float* __restrict__ y, unsigned short* __restrict__ tbT)
{
    __shared__ float tile[64][65];
    const int p0 = blockIdx.x * 64, c0 = blockIdx.y * 64;
    y += (size_t)blockIdx.z * 192 * 9216;
    tbT += (size_t)blockIdx.z * 9216 * 192;
    for (int i = threadIdx.x; i < 4096; i += 256) {
        int r = i >> 6, pcol = i & 63;
        const int c = c0 + r;
        const int pix = p0 + pcol;
        const float* yp = y + (size_t)c * 9216;
        float val;
        if (c0 == 64) {
            val = yp[pix];
        } else {
            const int oh = pix / 96, ow = pix % 96;
            float fh = fminf(fmaxf(oh * 0.5f - 0.25f, 0.f), 47.f);
            float fw = fminf(fmaxf(ow * 0.5f - 0.25f, 0.f), 47.f);
            int hlo = (int)floorf(fh);
            int wlo = (int)floorf(fw);
            int hhi = (hlo < 47) ? hlo + 1 : 47;
            int whi = (wlo < 47) ? wlo + 1 : 47;
            float ff = fh - (float)hlo;
            float fg = fw - (float)wlo;
            int hs[2] = {hlo, hhi}, wss[2] = {wlo, whi};
            float p[2][2];
            for (int a = 0; a < 2; ++a)
                for (int e = 0; e < 2; ++e) {
                    const float* q = yp + (hs[a] * 2) * 96 + wss[e] * 2;
                    float v00 = q[0], v01 = q[1], v10 = q[96], v11 = q[97];
                    p[a][e] = (c0 == 0)
                        ? fmaxf(fmaxf(v00, v01), fmaxf(v10, v11))
                        : 0.25f * (v00 + v01 + v10 + v11);
                }
            val = (p[0][0] * (1.f - ff) + p[1][0] * ff) * (1.f - fg)
                + (p[0][1] * (1.f - ff) + p[1][1] * ff) * fg;
        }
        tile[pcol][r] = val;
    }
    __syncthreads();
    for (int i = threadIdx.x; i < 2048; i += 256) {
        int p = i >> 5, cp = (i & 31) * 2;
        bf16 h0 = __float2bfloat16(tile[p][cp]);
        bf16 h1 = __float2bfloat16(tile[p][cp + 1]);
        unsigned int u = (unsigned int)(*reinterpret_cast<unsigned short*>(&h0))
                       | ((unsigned int)(*reinterpret_cast<unsigned short*>(&h1)) << 16);
        *reinterpret_cast<unsigned int*>(tbT + (size_t)(p0 + p) * 192 + c0 + cp) = u;
    }
}

// ------- implicit-im2col GEMM v5 -------------------------------------------
// out[B][M][9216] = A[M][9C] conv BT[B][9216][C], +BN+ReLU.
// Tile 64M x NT, BK=32, dbuf, 1 barrier/step, incremental-pointer staging.
// Granule swizzle as v4. gridDim = (9216/NT, M/64, B). C%32==0, NT in {128,256}.
template<int C, int NT>
__global__ __launch_bounds__(256)
void gemm_conv(const unsigned short* __restrict__ A,
               const unsigned short* __restrict__ BT,
               const unsigned short* __restrict__ zp,
               const float* __restrict__ sc, const float* __restrict__ sh,
               float* __restrict__ out, int M)
{
    constexpr int K = 9 * C;
    constexpr int nsteps = K / 32;     // 18 or 54 (even)
    constexpr int NSEC = NT / 64;      // B sections = gloads/thread = n-frags

    __shared__ __align__(16) unsigned short As[2][64 * 32];   // 2 x 4 KB
    __shared__ __align__(16) unsigned short Bs[2][NT * 32];   // 2 x NT/16 KB

    const int tid  = threadIdx.x;
    const int w    = tid >> 6;
    const int lane = tid & 63;
    const int l15  = lane & 15, quad = lane >> 4;

    BT  += (size_t)blockIdx.z * 9216 * C;
    out += (size_t)blockIdx.z * (size_t)M * 9216;

    const int row0 = blockIdx.y * 64;
    const int p0   = blockIdx.x * NT;

    f32x4 acc[4][NSEC];
#pragma unroll
    for (int m = 0; m < 4; ++m)
#pragma unroll
        for (int n = 0; n < NSEC; ++n) acc[m][n] = {0.f, 0.f, 0.f, 0.f};

    // staging geometry (v4): row srow, swizzled granule scol within 64B slice
    const int srow = tid >> 2;
    const int scol = (((tid & 3) ^ ((srow >> 1) & 3)) << 3);

    const unsigned short* sA = A + (size_t)(row0 + srow) * K + scol;  // +=32/step

    const unsigned short* bas[NSEC];
    unsigned vm[NSEC];
    {
        int hB[NSEC], wB[NSEC];
#pragma unroll
        for (int r = 0; r < NSEC; ++r) {
            int pB = p0 + 64 * r + srow;
            hB[r] = pB / 96; wB[r] = pB % 96;
            bas[r] = BT + (size_t)pB * C + scol;
            vm[r] = 0u;
        }
#pragma unroll
        for (int tap = 0; tap < 9; ++tap) {
            const int dh = tap / 3 - 1, dw = tap % 3 - 1;
#pragma unroll
            for (int r = 0; r < NSEC; ++r)
                vm[r] |= (unsigned)(((unsigned)(hB[r] + dh) < 96u) &&
                                    ((unsigned)(wB[r] + dw) < 96u)) << tap;
        }
    }

    int tap_s = 0, kk_s = 0;
    int offC_s = -97 * C;                  // pixel offset * C for stage tap
    const unsigned short* sel[NSEC];
#pragma unroll
    for (int r = 0; r < NSEC; ++r)
        sel[r] = (vm[r] & 1u) ? (bas[r] + offC_s) : zp;

    auto STAGE = [&](int pb) {
        gload16(sA, &As[0][0] + pb * 2048 + w * 512);
#pragma unroll
        for (int r = 0; r < NSEC; ++r)
            gload16(sel[r], &Bs[0][0] + pb * (NT * 32) + w * 512 + r * 2048);
    };
    auto ADV = [&]() {
        sA += 32;
        kk_s += 32;
        if (kk_s == C) {
            kk_s = 0; ++tap_s;
            offC_s += ((tap_s == 3) || (tap_s == 6)) ? 94 * C : C;
#pragma unroll
            for (int r = 0; r < NSEC; ++r)
                sel[r] = ((vm[r] >> tap_s) & 1u) ? (bas[r] + offC_s) : zp;
        } else {
#pragma unroll
            for (int r = 0; r < NSEC; ++r)
                sel[r] += 32;
        }
    };

    STAGE(0);
    ADV();
    __syncthreads();

    const int swz8 = (quad ^ ((l15 >> 1) & 3)) * 8;   // read granule (ushorts)

    auto COMPUTE = [&](auto pbc) {
        constexpr int PB = decltype(pbc)::value;
        const unsigned short* Ab = &As[0][0] + PB * 2048;
        const unsigned short* Bb = &Bs[0][0] + PB * (NT * 32);
        bf16x8 a[4], b[NSEC];
#pragma unroll
        for (int m = 0; m < 4; ++m)
            a[m] = *reinterpret_cast<const bf16x8*>(Ab + (m * 16 + l15) * 32 + swz8);
#pragma unroll
        for (int n = 0; n < NSEC; ++n)
            b[n] = *reinterpret_cast<const bf16x8*>(
                Bb + (w * (NT / 4) + n * 16 + l15) * 32 + swz8);
#pragma unroll
        for (int m = 0; m < 4; ++m)
#pragma unroll
            for (int n = 0; n < NSEC; ++n)
                acc[m][n] = __builtin_amdgcn_mfma_f32_16x16x32_bf16(
                    a[m], b[n], acc[m][n], 0, 0, 0);
    };

    for (int s = 0; s < nsteps; s += 2) {
        if (s + 1 < nsteps) { STAGE(1); ADV(); }
        COMPUTE(std::integral_constant<int, 0>{});
        __syncthreads();
        if (s + 2 < nsteps) { STAGE(0); ADV(); }
        COMPUTE(std::integral_constant<int, 1>{});
        __syncthreads();
    }

#pragma unroll
    for (int m = 0; m < 4; ++m) {
        const int co = row0 + m * 16 + quad * 4;
#pragma unroll
        for (int n = 0; n < NSEC; ++n) {
            const int pix = p0 + w * (NT / 4) + n * 16 + l15;
#pragma unroll
            for (int r = 0; r < 4; ++r) {
                const int c = co + r;
                float v = acc[m][n][r] * sc[c] + sh[c];
                out[(size_t)c * 9216 + pix] = fmaxf(v, 0.f);
            }
        }
    }
}

// ------------- l2norm rows (block per row, shuffle reduce); grid (384,B) ---
__global__ __launch_bounds__(256)
void l2norm_rows(float* __restrict__ t2)
{
    const int c = blockIdx.x;
    float* p = t2 + (size_t)blockIdx.y * 5308416 + (size_t)c * 9216;
    float s = 0.f;
    for (int i = threadIdx.x; i < 9216; i += 256) { float v = p[i]; s += v * v; }
    for (int off = 32; off; off >>= 1) s += __shfl_xor(s, off, 64);
    __shared__ float red[4];
    if ((threadIdx.x & 63) == 0) red[threadIdx.x >> 6] = s;
    __syncthreads();
    float tot = red[0] + red[1] + red[2] + red[3];
    float inv = 1.f / fmaxf(sqrtf(tot), 1e-12f);
    for (int i = threadIdx.x; i < 9216; i += 256) p[i] *= inv;
}

// -------- qk split-K partial: pk[b][z][c][d], 64x64 tile, 4x4/thread -------
__global__ __launch_bounds__(256)
void qk_partial(const float* __restrict__ t2, float* __restrict__ pk)
{
    __shared__ __align__(16) float qs[32][68];
    __shared__ __align__(16) float ks[32][68];
    const int c0 = blockIdx.y * 64, d0 = blockIdx.x * 64;
    const int bz = blockIdx.z, bb = bz >> 3, chunk = bz & 7;
    const int kbase = chunk * 1152;
    const int tid = threadIdx.x, tx = tid & 15, ty = tid >> 4;
    const float* qb = t2 + (size_t)bb * 5308416;
    const float* kb = qb + (size_t)192 * 9216;

    float acc[4][4];
#pragma unroll
    for (int i = 0; i < 4; ++i)
#pragma unroll
        for (int j = 0; j < 4; ++j) acc[i][j] = 0.f;

    for (int n0 = 0; n0 < 1152; n0 += 32) {
        for (int i = tid; i < 512; i += 256) {
            int row = i >> 3, col = (i & 7) * 4;
            f32x4 v = *reinterpret_cast<const f32x4*>(
                qb + (size_t)(c0 + row) * 9216 + kbase + n0 + col);
            qs[col + 0][row] = v[0];
            qs[col + 1][row] = v[1];
            qs[col + 2][row] = v[2];
            qs[col + 3][row] = v[3];
            f32x4 w = *reinterpret_cast<const f32x4*>(
                kb + (size_t)(d0 + row) * 9216 + kbase + n0 + col);
            ks[col + 0][row] = w[0];
            ks[col + 1][row] = w[1];
            ks[col + 2][row] = w[2];
            ks[col + 3][row] = w[3];
        }
        __syncthreads();
#pragma unroll
        for (int kk = 0; kk < 32; ++kk) {
            f32x4 q4 = *reinterpret_cast<const f32x4*>(&qs[kk][ty * 4]);
            f32x4 k4 = *reinterpret_cast<const f32x4*>(&ks[kk][tx * 4]);
#pragma unroll
            for (int i = 0; i < 4; ++i)
#pragma unroll
                for (int j = 0; j < 4; ++j)
                    acc[i][j] += q4[i] * k4[j];
        }
        __syncthreads();
    }

    float* dst = pk + (size_t)bz * 36864;
#pragma unroll
    for (int i = 0; i < 4; ++i)
#pragma unroll
        for (int j = 0; j < 4; ++j)
            dst[(size_t)(c0 + ty * 4 + i) * 192 + d0 + tx * 4 + j] = acc[i][j];
}

// -------- qk reduce: attn[b][i] = temp * sum_z pk[b][z][i]; grid (144,B) ---
__global__ __launch_bounds__(256)
void qk_reduce(const float* __restrict__ pk, const float* __restrict__ temp,
               float* __restrict__ attn)
{
    const int i = blockIdx.x * 256 + threadIdx.x;
    if (i >= 36864) return;
    const int bb = blockIdx.y;
    const float* src = pk + (size_t)bb * 8 * 36864;
    float s = 0.f;
#pragma unroll
    for (int k = 0; k < 8; ++k)
        s += src[(size_t)k * 36864 + i];
    attn[(size_t)bb * 36864 + i] = s * temp[0];
}

// ---------------- softmax over last dim (192); grid (192*B) ----------------
__global__ __launch_bounds__(64)
void softmax192(float* __restrict__ attn)
{
    float* p = attn + (size_t)blockIdx.x * 192;
    const int t = threadIdx.x;
    float e0 = p[t], e1 = p[t + 64], e2 = p[t + 128];
    float m = fmaxf(e0, fmaxf(e1, e2));
    for (int off = 32; off; off >>= 1) m = fmaxf(m, __shfl_xor(m, off, 64));
    e0 = __expf(e0 - m); e1 = __expf(e1 - m); e2 = __expf(e2 - m);
    float s = e0 + e1 + e2;
    for (int off = 32; off; off >>= 1) s += __shfl_xor(s, off, 64);
    float inv = 1.f / s;
    p[t] = e0 * inv; p[t + 64] = e1 * inv; p[t + 128] = e2 * inv;
}

// ------- ao = attn @ v; grid (36, 12, B) -----------------------------------
__global__ __launch_bounds__(256)
void attn_v(const float* __restrict__ attn, const float* __restrict__ t2,
            float* __restrict__ ao)
{
    __shared__ float aL[192 * 16];
    const int c0 = blockIdx.y * 16;
    const int n = blockIdx.x * 256 + threadIdx.x;
    attn += (size_t)blockIdx.z * 36864;
    t2   += (size_t)blockIdx.z * 5308416;
    ao   += (size_t)blockIdx.z * 1769472;
    for (int i = threadIdx.x; i < 3072; i += 256) {
        int d = i >> 4, cc = i & 15;
        aL[d * 16 + cc] = attn[(size_t)(c0 + cc) * 192 + d];
    }
    __syncthreads();
    const float* vb = t2 + (size_t)384 * 9216;
    f32x4 acc[4];
#pragma unroll
    for (int j = 0; j < 4; ++j) acc[j] = {0.f, 0.f, 0.f, 0.f};
    for (int d = 0; d < 192; ++d) {
        float vv = vb[(size_t)d * 9216 + n];
        const f32x4* ap = reinterpret_cast<const f32x4*>(&aL[d * 16]);
#pragma unroll
        for (int j = 0; j < 4; ++j) {
            f32x4 a = ap[j];
            acc[j][0] += a[0] * vv;
            acc[j][1] += a[1] * vv;
            acc[j][2] += a[2] * vv;
            acc[j][3] += a[3] * vv;
        }
    }
#pragma unroll
    for (int j = 0; j < 4; ++j)
#pragma unroll
        for (int r = 0; r < 4; ++r)
            ao[(size_t)(c0 + j * 4 + r) * 9216 + n] = acc[j][r];
}

// ---------------- depthwise 3x3 + bias -> fp32 out; grid (36,192,B) --------
__global__ __launch_bounds__(256)
void dwconv(const float* __restrict__ ao, const float* __restrict__ w2,
            const float* __restrict__ bias2, float* __restrict__ out)
{
    const int c = blockIdx.y;
    const int pix = blockIdx.x * 256 + threadIdx.x;
    const int h = pix / 96, w = pix % 96;
    const float* sp = ao + (size_t)blockIdx.z * 1769472 + (size_t)c * 9216;
    float acc = bias2[c];
#pragma unroll
    for (int kh = 0; kh < 3; ++kh) {
        int hh = h + kh - 1;
        if (hh < 0 || hh >= 96) continue;
#pragma unroll
        for (int kw = 0; kw < 3; ++kw) {
            int ww = w + kw - 1;
            if (ww < 0 || ww >= 96) continue;
            acc += w2[c * 9 + kh * 3 + kw] * sp[hh * 96 + ww];
        }
    }
    out[(size_t)blockIdx.z * 1769472 + (size_t)c * 9216 + pix] = acc;
}

extern "C" void kernel_launch(void* const* d_in, const int* in_sizes, int n_in,
                              void* d_out, int out_size, void* d_ws, size_t ws_size,
                              hipStream_t stream)
{
    float* out = (float*)d_out;

    static const int expected_sizes[16] = {
        2359296, 110592, 192, 192, 192, 192, 192,
        995328, 576, 576, 576, 576, 576, 1, 1728, 192
    };
    if (n_in != 16) {
        beacon_kernel<<<1, 256, 0, stream>>>(out, 100000.f + (float)n_in);
        return;
    }
    for (int i = 0; i < 16; ++i) {
        if (in_sizes[i] != expected_sizes[i]) {
            beacon_kernel<<<1, 256, 0, stream>>>(out, 1000.f * (float)(i + 1));
            return;
        }
    }
    if (out_size != 7077888) {
        beacon_kernel<<<1, 256, 0, stream>>>(out, 50000.f);
        return;
    }
    const size_t needed = (size_t)34912000 * 4;  // 139.65 MB
    if (ws_size < needed) {
        beacon_kernel<<<1, 256, 0, stream>>>(out, 200.f + (float)(ws_size >> 20));
        return;
    }

    const float* x    = (const float*)d_in[0];
    const float* w0   = (const float*)d_in[1];
    const float* b0   = (const float*)d_in[2];
    const float* g0   = (const float*)d_in[3];
    const float* be0  = (const float*)d_in[4];
    const float* m0   = (const float*)d_in[5];
    const float* v0   = (const float*)d_in[6];
    const float* w1   = (const float*)d_in[7];
    const float* b1   = (const float*)d_in[8];
    const float* g1   = (const float*)d_in[9];
    const float* be1  = (const float*)d_in[10];
    const float* m1   = (const float*)d_in[11];
    const float* v1   = (const float*)d_in[12];
    const float* temp = (const float*)d_in[13];
    const float* w2   = (const float*)d_in[14];
    const float* bi2  = (const float*)d_in[15];

    float* ws    = (float*)d_ws;
    float* yb    = ws;                        // 4 x 1,769,472 f
    float* t2b   = ws + 7077888;              // 4 x 5,308,416 f
    float* attnb = ws + 28311552;             // 4 x 36,864 f
    float* sc0   = ws + 28459008;
    float* sh0   = ws + 28459200;
    float* sc1   = ws + 28459392;
    float* sh1   = ws + 28459968;
    float* zpf   = ws + 28460544;             // 256 f zero page
    unsigned short* zp  = (unsigned short*)zpf;
    unsigned short* A0  = (unsigned short*)(ws + 28460800);  // 110,592 bf16
    unsigned short* A1  = (unsigned short*)(ws + 28516096);  // 995,328 bf16
    unsigned short* xT  = (unsigned short*)(ws + 29013760);  // 4 x 9216x64 bf16
    unsigned short* tbT = (unsigned short*)(ws + 30193408);  // 4 x 9216x192 bf16
    float* pk  = ws + 33732352;               // 4 x 8 x 36864 f
    float* aob = yb;  // alias: yb dead after build_tT

    wreorder_kernel<<<dim3(432), dim3(256), 0, stream>>>(w0, A0, 64, 110592);
    wreorder_kernel<<<dim3(3888), dim3(256), 0, stream>>>(w1, A1, 192, 995328);
    bnfold_kernel<<<dim3(4), dim3(256), 0, stream>>>(g0, b0, be0, m0, v0,
                                                     g1, b1, be1, m1, v1,
                                                     sc0, sh0, sc1, sh1, zpf);

    txpose_kernel<<<dim3(144, 1, 4), dim3(256), 0, stream>>>(x, xT, 64);
    gemm_conv<64, 128><<<dim3(72, 3, 4), dim3(256), 0, stream>>>(A0, xT, zp, sc0, sh0, yb, 192);
    build_tT<<<dim3(144, 3, 4), dim3(256), 0, stream>>>(yb, tbT);
    gemm_conv<192, 256><<<dim3(36, 9, 4), dim3(256), 0, stream>>>(A1, tbT, zp, sc1, sh1, t2b, 576);
    l2norm_rows<<<dim3(384, 4), dim3(256), 0, stream>>>(t2b);
    qk_partial<<<dim3(3, 3, 32), dim3(256), 0, stream>>>(t2b, pk);
    qk_reduce<<<dim3(144, 4), dim3(256), 0, stream>>>(pk, temp, attnb);
    softmax192<<<dim3(768), dim3(64), 0, stream>>>(attnb);
    attn_v<<<dim3(36, 12, 4), dim3(256), 0, stream>>>(attnb, t2b, aob);
    dwconv<<<dim3(36, 192, 4), dim3(256), 0, stream>>>(aob, w2, bi2, out);
}